// Round 2
// baseline (5150.569 us; speedup 1.0000x reference)
//
#include <hip/hip_runtime.h>
#include <hip/hip_bf16.h>

#define BB 8
#define CC 512
#define CI 64
#define HH 97
#define WW 97
#define HWP 9409          // H*W
#define NPOS 75272        // B*H*W
#define ATT 194           // H+W
#define NEG_INF_F (-1000000000.0f)

// ---------------- transpose (B,C,H,W) -> channels-last [b,p,c] ----------------
__global__ __launch_bounds__(256) void t_in(const float* __restrict__ x, float* __restrict__ xcl) {
    __shared__ float t[32][33];
    int b = blockIdx.z, p0 = blockIdx.x * 32, c0 = blockIdx.y * 32;
    #pragma unroll
    for (int i = 0; i < 4; ++i) {
        int c = c0 + threadIdx.y + 8 * i, p = p0 + threadIdx.x;
        float v = 0.f;
        if (p < HWP) v = x[((size_t)b * CC + c) * HWP + p];
        t[threadIdx.y + 8 * i][threadIdx.x] = v;
    }
    __syncthreads();
    #pragma unroll
    for (int i = 0; i < 4; ++i) {
        int p = p0 + threadIdx.y + 8 * i, c = c0 + threadIdx.x;
        if (p < HWP) xcl[((size_t)b * HWP + p) * CC + c] = t[threadIdx.x][threadIdx.y + 8 * i];
    }
}

__global__ __launch_bounds__(256) void t_out(const float* __restrict__ xcl, float* __restrict__ x) {
    __shared__ float t[32][33];
    int b = blockIdx.z, p0 = blockIdx.x * 32, c0 = blockIdx.y * 32;
    #pragma unroll
    for (int i = 0; i < 4; ++i) {
        int p = p0 + threadIdx.y + 8 * i, c = c0 + threadIdx.x;
        float v = 0.f;
        if (p < HWP) v = xcl[((size_t)b * HWP + p) * CC + c];
        t[threadIdx.y + 8 * i][threadIdx.x] = v;
    }
    __syncthreads();
    #pragma unroll
    for (int i = 0; i < 4; ++i) {
        int c = c0 + threadIdx.y + 8 * i, p = p0 + threadIdx.x;
        if (p < HWP) x[((size_t)b * CC + c) * HWP + p] = t[threadIdx.x][threadIdx.y + 8 * i];
    }
}

// weight transpose (O x Cn) -> (Cn x O)
__global__ void t_w(const float* __restrict__ w, float* __restrict__ wt, int O, int Cn) {
    int i = blockIdx.x * 256 + threadIdx.x;
    if (i < O * Cn) { int o = i / Cn, c = i - o * Cn; wt[c * O + o] = w[i]; }
}

// ---------------- q,k projection: [NPOS x 512] @ [512 x 128] -> q[NPOS x 64], k[NPOS x 64]
__global__ __launch_bounds__(256) void qkproj(const float* __restrict__ xin,
                                              const float* __restrict__ wqT, const float* __restrict__ wkT,
                                              const float* __restrict__ bq, const float* __restrict__ bk,
                                              float* __restrict__ q, float* __restrict__ k) {
    size_t row0 = (size_t)blockIdx.x * 64;
    __shared__ float As[16][68];
    __shared__ float Bs[16][128];
    int t = threadIdx.x, rg = t >> 5, cg = t & 31;
    float acc[8][4] = {{0.f}};
    for (int k0 = 0; k0 < 512; k0 += 16) {
        #pragma unroll
        for (int u = 0; u < 4; ++u) {
            int idx = u * 256 + t; int r = idx >> 4, kl = idx & 15;
            float vv = 0.f; size_t row = row0 + r;
            if (row < NPOS) vv = xin[row * 512 + k0 + kl];
            As[kl][r] = vv;
        }
        #pragma unroll
        for (int u = 0; u < 2; ++u) {
            int f = u * 256 + t; int kl = f >> 5, n4 = (f & 31) * 4;
            const float* src = (n4 < 64) ? &wqT[(size_t)(k0 + kl) * 64 + n4]
                                         : &wkT[(size_t)(k0 + kl) * 64 + (n4 - 64)];
            *(float4*)&Bs[kl][n4] = *(const float4*)src;
        }
        __syncthreads();
        #pragma unroll
        for (int kk = 0; kk < 16; ++kk) {
            float ra[8];
            *(float4*)&ra[0] = *(float4*)&As[kk][rg * 8];
            *(float4*)&ra[4] = *(float4*)&As[kk][rg * 8 + 4];
            #pragma unroll
            for (int j = 0; j < 4; ++j) {
                float xb = Bs[kk][cg + 32 * j];
                #pragma unroll
                for (int i = 0; i < 8; ++i) acc[i][j] += ra[i] * xb;
            }
        }
        __syncthreads();
    }
    #pragma unroll
    for (int i = 0; i < 8; ++i) {
        size_t row = row0 + rg * 8 + i;
        if (row < NPOS) {
            #pragma unroll
            for (int j = 0; j < 4; ++j) {
                int n = cg + 32 * j;
                if (n < 64) q[row * 64 + n] = acc[i][j] + bq[n];
                else        k[row * 64 + (n - 64)] = acc[i][j] + bk[n - 64];
            }
        }
    }
}

// ---------------- eH per (b,w): eH[h][g] = q(h,w)·k(g,w), diag masked ----------------
__global__ __launch_bounds__(256) void att_col(const float* __restrict__ q, const float* __restrict__ k,
                                               float* __restrict__ att) {
    int w = blockIdx.x, b = blockIdx.y;
    __shared__ float Qs[97][68];
    __shared__ float Ks[97][68];
    int t = threadIdx.x;
    for (int u = 0; u < 7; ++u) {
        int h = u * 16 + (t >> 4); int c4 = (t & 15) * 4;
        if (h < 97) {
            size_t base = ((size_t)((b * 97 + h) * 97 + w)) * 64 + c4;
            *(float4*)&Qs[h][c4] = *(const float4*)&q[base];
            *(float4*)&Ks[h][c4] = *(const float4*)&k[base];
        }
    }
    __syncthreads();
    for (int i = t; i < 9409; i += 256) {
        int h = i / 97, g = i - h * 97;
        float s = 0.f;
        #pragma unroll
        for (int c = 0; c < 64; c += 4) {
            float4 a = *(float4*)&Qs[h][c];
            float4 bb = *(float4*)&Ks[g][c];
            s += a.x * bb.x + a.y * bb.y + a.z * bb.z + a.w * bb.w;
        }
        if (g == h) s += NEG_INF_F;
        att[((size_t)((b * 97 + h) * 97 + w)) * ATT + g] = s;
    }
}

// ---------------- eW per (b,h) + fused softmax over concat[eH|eW] ----------------
__global__ __launch_bounds__(256) void att_row_sm(const float* __restrict__ q, const float* __restrict__ k,
                                                  float* __restrict__ att) {
    int h = blockIdx.x, b = blockIdx.y;
    __shared__ float Qs[97][68];
    __shared__ float Ks[97][68];
    __shared__ float Es[16][100];
    int t = threadIdx.x;
    size_t rowbase = (size_t)(b * 97 + h) * 97;
    for (int u = 0; u < 7; ++u) {
        int v = u * 16 + (t >> 4); int c4 = (t & 15) * 4;
        if (v < 97) {
            size_t base = (rowbase + v) * 64 + c4;
            *(float4*)&Qs[v][c4] = *(const float4*)&q[base];
            *(float4*)&Ks[v][c4] = *(const float4*)&k[base];
        }
    }
    __syncthreads();
    int grp = t >> 4, lj = t & 15;
    for (int w0 = 0; w0 < 97; w0 += 16) {
        int wcnt = (97 - w0) < 16 ? (97 - w0) : 16;
        for (int i = t; i < wcnt * 97; i += 256) {
            int wl = i / 97, v = i - wl * 97;
            float s = 0.f;
            #pragma unroll
            for (int c = 0; c < 64; c += 4) {
                float4 a = *(float4*)&Qs[w0 + wl][c];
                float4 bb = *(float4*)&Ks[v][c];
                s += a.x * bb.x + a.y * bb.y + a.z * bb.z + a.w * bb.w;
            }
            Es[wl][v] = s;
        }
        __syncthreads();
        if (grp < wcnt) {
            int w = w0 + grp;
            size_t arow = (rowbase + w) * ATT;
            float vals[13];
            float m = -3.4e38f;
            #pragma unroll
            for (int u = 0; u < 13; ++u) {
                int col = lj + 16 * u;
                float vv = -3.4e38f;
                if (col < ATT) vv = (col < 97) ? att[arow + col] : Es[grp][col - 97];
                vals[u] = vv;
                m = fmaxf(m, vv);
            }
            #pragma unroll
            for (int off = 8; off >= 1; off >>= 1) m = fmaxf(m, __shfl_xor(m, off, 16));
            float ssum = 0.f;
            #pragma unroll
            for (int u = 0; u < 13; ++u) {
                int col = lj + 16 * u;
                if (col < ATT) { vals[u] = __expf(vals[u] - m); ssum += vals[u]; }
            }
            #pragma unroll
            for (int off = 8; off >= 1; off >>= 1) ssum += __shfl_xor(ssum, off, 16);
            float inv = 1.0f / ssum;
            #pragma unroll
            for (int u = 0; u < 13; ++u) {
                int col = lj + 16 * u;
                if (col < ATT) att[arow + col] = vals[u] * inv;
            }
        }
        __syncthreads();
    }
}

// ---------------- column gather: agg_part[b,h,w,:] = sum_g aH[h,w,g] * x[b,g,w,:] (overwrite)
__global__ __launch_bounds__(256) void gath_col(const float* __restrict__ att, const float* __restrict__ xin,
                                                float* __restrict__ xout) {
    int b = blockIdx.z, w = blockIdx.y, half = blockIdx.x;
    int h0 = half * 64;
    __shared__ float As[16][68];
    __shared__ float Xs[16][512];
    int t = threadIdx.x, rg = t >> 5, cg = t & 31;
    float acc[8][16] = {{0.f}};
    for (int k0 = 0; k0 < 97; k0 += 16) {
        #pragma unroll
        for (int u = 0; u < 4; ++u) {
            int idx = u * 256 + t, gl = idx & 15, hh = idx >> 4;
            int g = k0 + gl, h = h0 + hh;
            float vv = 0.f;
            if (g < 97 && h < 97) vv = att[((size_t)((b * 97 + h) * 97 + w)) * ATT + g];
            As[gl][hh] = vv;
        }
        #pragma unroll
        for (int u = 0; u < 8; ++u) {
            int f = u * 256 + t; int gl = f >> 7, c4 = (f & 127) * 4;
            int g = k0 + gl;
            float4 vv = make_float4(0.f, 0.f, 0.f, 0.f);
            if (g < 97) vv = *(const float4*)&xin[((size_t)((b * 97 + g) * 97 + w)) * 512 + c4];
            *(float4*)&Xs[gl][c4] = vv;
        }
        __syncthreads();
        #pragma unroll
        for (int kk = 0; kk < 16; ++kk) {
            float ra[8];
            *(float4*)&ra[0] = *(float4*)&As[kk][rg * 8];
            *(float4*)&ra[4] = *(float4*)&As[kk][rg * 8 + 4];
            #pragma unroll
            for (int j = 0; j < 16; ++j) {
                float xb = Xs[kk][cg + 32 * j];
                #pragma unroll
                for (int i = 0; i < 8; ++i) acc[i][j] += ra[i] * xb;
            }
        }
        __syncthreads();
    }
    #pragma unroll
    for (int i = 0; i < 8; ++i) {
        int h = h0 + rg * 8 + i;
        if (h < 97) {
            size_t base = ((size_t)((b * 97 + h) * 97 + w)) * 512;
            #pragma unroll
            for (int j = 0; j < 16; ++j) xout[base + cg + 32 * j] = acc[i][j];
        }
    }
}

// ---------------- row gather: agg[b,h,w,:] += sum_v aW[h,w,v] * x[b,h,v,:] ----------------
__global__ __launch_bounds__(256) void gath_row(const float* __restrict__ att, const float* __restrict__ xin,
                                                float* __restrict__ xout) {
    int b = blockIdx.z, h = blockIdx.y, half = blockIdx.x;
    int w0 = half * 64;
    __shared__ float As[16][68];
    __shared__ float Xs[16][512];
    int t = threadIdx.x, rg = t >> 5, cg = t & 31;
    float acc[8][16] = {{0.f}};
    size_t rowbase = (size_t)(b * 97 + h) * 97;
    for (int k0 = 0; k0 < 97; k0 += 16) {
        #pragma unroll
        for (int u = 0; u < 4; ++u) {
            int idx = u * 256 + t, gl = idx & 15, wl = idx >> 4;
            int g = k0 + gl, w = w0 + wl;
            float vv = 0.f;
            if (g < 97 && w < 97) vv = att[(rowbase + w) * ATT + 97 + g];
            As[gl][wl] = vv;
        }
        #pragma unroll
        for (int u = 0; u < 8; ++u) {
            int f = u * 256 + t; int gl = f >> 7, c4 = (f & 127) * 4;
            int g = k0 + gl;
            float4 vv = make_float4(0.f, 0.f, 0.f, 0.f);
            if (g < 97) vv = *(const float4*)&xin[(rowbase + g) * 512 + c4];
            *(float4*)&Xs[gl][c4] = vv;
        }
        __syncthreads();
        #pragma unroll
        for (int kk = 0; kk < 16; ++kk) {
            float ra[8];
            *(float4*)&ra[0] = *(float4*)&As[kk][rg * 8];
            *(float4*)&ra[4] = *(float4*)&As[kk][rg * 8 + 4];
            #pragma unroll
            for (int j = 0; j < 16; ++j) {
                float xb = Xs[kk][cg + 32 * j];
                #pragma unroll
                for (int i = 0; i < 8; ++i) acc[i][j] += ra[i] * xb;
            }
        }
        __syncthreads();
    }
    #pragma unroll
    for (int i = 0; i < 8; ++i) {
        int w = w0 + rg * 8 + i;
        if (w < 97) {
            size_t base = (rowbase + w) * 512;
            #pragma unroll
            for (int j = 0; j < 16; ++j) {
                int c = cg + 32 * j;
                xout[base + c] += acc[i][j];
            }
        }
    }
}

// ---------------- projection (in-place): xio = gamma*(xio @ WvT + bv) + xres ----------------
__global__ __launch_bounds__(256) void proj(const float* __restrict__ wvT, const float* __restrict__ bv,
                                            const float* __restrict__ gptr, const float* __restrict__ xres,
                                            float* __restrict__ xio) {
    size_t row0 = (size_t)blockIdx.x * 64;
    __shared__ float As[16][68];
    __shared__ float Bs[16][512];
    int t = threadIdx.x, rg = t >> 5, cg = t & 31;
    float acc[8][16] = {{0.f}};
    for (int k0 = 0; k0 < 512; k0 += 16) {
        #pragma unroll
        for (int u = 0; u < 4; ++u) {
            int idx = u * 256 + t; int r = idx >> 4, kl = idx & 15;
            float vv = 0.f; size_t row = row0 + r;
            if (row < NPOS) vv = xio[row * 512 + k0 + kl];
            As[kl][r] = vv;
        }
        #pragma unroll
        for (int u = 0; u < 8; ++u) {
            int f = u * 256 + t; int kl = f >> 7, c4 = (f & 127) * 4;
            *(float4*)&Bs[kl][c4] = *(const float4*)&wvT[(size_t)(k0 + kl) * 512 + c4];
        }
        __syncthreads();
        #pragma unroll
        for (int kk = 0; kk < 16; ++kk) {
            float ra[8];
            *(float4*)&ra[0] = *(float4*)&As[kk][rg * 8];
            *(float4*)&ra[4] = *(float4*)&As[kk][rg * 8 + 4];
            #pragma unroll
            for (int j = 0; j < 16; ++j) {
                float xb = Bs[kk][cg + 32 * j];
                #pragma unroll
                for (int i = 0; i < 8; ++i) acc[i][j] += ra[i] * xb;
            }
        }
        __syncthreads();
    }
    float gm = *gptr;
    #pragma unroll
    for (int i = 0; i < 8; ++i) {
        size_t row = row0 + rg * 8 + i;
        if (row < NPOS) {
            #pragma unroll
            for (int j = 0; j < 16; ++j) {
                int c = cg + 32 * j;
                xio[row * 512 + c] = gm * (acc[i][j] + bv[c]) + xres[row * 512 + c];
            }
        }
    }
}

extern "C" void kernel_launch(void* const* d_in, const int* in_sizes, int n_in,
                              void* d_out, int out_size, void* d_ws, size_t ws_size,
                              hipStream_t stream) {
    const float* x_in  = (const float*)d_in[0];
    const float* Wq    = (const float*)d_in[1];
    const float* bq    = (const float*)d_in[2];
    const float* Wk    = (const float*)d_in[3];
    const float* bk    = (const float*)d_in[4];
    const float* Wv    = (const float*)d_in[5];
    const float* bv    = (const float*)d_in[6];
    const float* gamma = (const float*)d_in[7];

    float* ws  = (float*)d_ws;
    float* xA  = ws;
    float* q   = xA + (size_t)NPOS * CC;
    float* kk  = q  + (size_t)NPOS * CI;
    float* att = kk + (size_t)NPOS * CI;
    float* wqT = att + (size_t)NPOS * ATT;
    float* wkT = wqT + 512 * 64;
    float* wvT = wkT + 512 * 64;
    float* xB  = (float*)d_out;   // d_out doubles as channels-last scratch between iterations

    t_w<<<(64 * 512 + 255) / 256, 256, 0, stream>>>(Wq, wqT, 64, 512);
    t_w<<<(64 * 512 + 255) / 256, 256, 0, stream>>>(Wk, wkT, 64, 512);
    t_w<<<(512 * 512 + 255) / 256, 256, 0, stream>>>(Wv, wvT, 512, 512);
    t_in<<<dim3(295, 16, 8), dim3(32, 8), 0, stream>>>(x_in, xA);

    const float* xi = xA;
    float* xo = xB;
    for (int it = 0; it < 2; ++it) {
        qkproj<<<1177, 256, 0, stream>>>(xi, wqT, wkT, bq, bk, q, kk);
        att_col<<<dim3(97, 8), 256, 0, stream>>>(q, kk, att);
        att_row_sm<<<dim3(97, 8), 256, 0, stream>>>(q, kk, att);
        gath_col<<<dim3(2, 97, 8), 256, 0, stream>>>(att, xi, xo);
        gath_row<<<dim3(2, 97, 8), 256, 0, stream>>>(att, xi, xo);
        proj<<<1177, 256, 0, stream>>>(wvT, bv, gamma, xi, xo);
        float* tmp = (float*)xi; xi = xo; xo = tmp;
    }
    // after 2 iterations result is channels-last in xi (== xA); convert to (B,C,H,W)
    t_out<<<dim3(295, 16, 8), dim3(32, 8), 0, stream>>>(xi, (float*)d_out);
}

// Round 4
// 2959.193 us; speedup vs baseline: 1.7405x; 1.7405x over previous
//
#include <hip/hip_runtime.h>
#include <hip/hip_bf16.h>

#define BB 8
#define CC 512
#define CI 64
#define HH 97
#define WW 97
#define HWP 9409          // H*W
#define NPOS 75272        // B*H*W
#define ATT 194           // H+W
#define NEG_INF_F (-1000000000.0f)

typedef unsigned short u16;
typedef unsigned int u32;
typedef __attribute__((ext_vector_type(8))) short short8;
typedef __attribute__((ext_vector_type(4))) float f32x4;

__device__ inline u16 f2bf(float f) {
    u32 x = __float_as_uint(f);
    return (u16)((x + 0x7fffu + ((x >> 16) & 1u)) >> 16);
}
__device__ inline float bf2f(u16 u) { return __uint_as_float(((u32)u) << 16); }

// ---------------- transpose (B,C,H,W) -> channels-last [b,p,c] ----------------
__global__ __launch_bounds__(256) void t_in(const float* __restrict__ x, float* __restrict__ xcl) {
    __shared__ float t[32][33];
    int b = blockIdx.z, p0 = blockIdx.x * 32, c0 = blockIdx.y * 32;
    #pragma unroll
    for (int i = 0; i < 4; ++i) {
        int c = c0 + threadIdx.y + 8 * i, p = p0 + threadIdx.x;
        float v = 0.f;
        if (p < HWP) v = x[((size_t)b * CC + c) * HWP + p];
        t[threadIdx.y + 8 * i][threadIdx.x] = v;
    }
    __syncthreads();
    #pragma unroll
    for (int i = 0; i < 4; ++i) {
        int p = p0 + threadIdx.y + 8 * i, c = c0 + threadIdx.x;
        if (p < HWP) xcl[((size_t)b * HWP + p) * CC + c] = t[threadIdx.x][threadIdx.y + 8 * i];
    }
}

__global__ __launch_bounds__(256) void t_out(const float* __restrict__ xcl, float* __restrict__ x) {
    __shared__ float t[32][33];
    int b = blockIdx.z, p0 = blockIdx.x * 32, c0 = blockIdx.y * 32;
    #pragma unroll
    for (int i = 0; i < 4; ++i) {
        int p = p0 + threadIdx.y + 8 * i, c = c0 + threadIdx.x;
        float v = 0.f;
        if (p < HWP) v = xcl[((size_t)b * HWP + p) * CC + c];
        t[threadIdx.y + 8 * i][threadIdx.x] = v;
    }
    __syncthreads();
    #pragma unroll
    for (int i = 0; i < 4; ++i) {
        int c = c0 + threadIdx.y + 8 * i, p = p0 + threadIdx.x;
        if (p < HWP) x[((size_t)b * CC + c) * HWP + p] = t[threadIdx.x][threadIdx.y + 8 * i];
    }
}

// ---------------- weight conversions to bf16 ----------------
__global__ void cvt_qkw(const float* __restrict__ wq, const float* __restrict__ wk, u16* __restrict__ o) {
    int i = blockIdx.x * 256 + threadIdx.x;  // 0..65535
    float v = (i < 32768) ? wq[i] : wk[i - 32768];
    o[i] = f2bf(v);
}
__global__ void cvt_vw(const float* __restrict__ wv, u16* __restrict__ o) {
    int i = blockIdx.x * 256 + threadIdx.x;  // 0..262143
    o[i] = f2bf(wv[i]);
}

// ---------------- MFMA GEMM: C[row][n] = sum_k A[row][k]*W[n][k] (+bias epilogue) ----------
// A: [NPOS][512] fp32 (converted to bf16 during LDS staging)
// Bw: [N][512] bf16 row-major (k contiguous) -- W as given, no transpose needed
// EPI 0: split q|k fp32 outputs (N=128).  EPI 1: v bf16 output (N=512).
template<int EPI>
__global__ __launch_bounds__(256) void gemm_mfma(
    const float* __restrict__ A, const u16* __restrict__ Bw,
    const float* __restrict__ b0, const float* __restrict__ b1,
    float* __restrict__ o0, float* __restrict__ o1, u16* __restrict__ ov)
{
    __shared__ uint4 ldsu4[1024];   // 16 KB: A tile [0,8192), B tile [8192,16384)
    char* lds = (char*)ldsu4;
    const int t = threadIdx.x;
    const size_t row0 = (size_t)blockIdx.y * 128;
    const int n0 = blockIdx.x * 128;
    const int wv = t >> 6, lane = t & 63;
    const int wm = wv >> 1, wn = wv & 1;
    const int lr = lane & 15, lg = lane >> 4;

    f32x4 acc[4][4];
    const f32x4 fz = {0.f, 0.f, 0.f, 0.f};
    #pragma unroll
    for (int i = 0; i < 4; ++i)
        #pragma unroll
        for (int j = 0; j < 4; ++j) acc[i][j] = fz;

    const int am = t >> 3;   // 0..31: row within 32-row group
    const int kq = t & 7;    // which float4 along k (k = kq*4..kq*4+3)

    for (int k0 = 0; k0 < 512; k0 += 32) {
        // stage A: 128 rows x 32 k, fp32 -> bf16, swizzled slots
        #pragma unroll
        for (int u = 0; u < 4; ++u) {
            int m = u * 32 + am;
            size_t row = row0 + m;
            float4 av = make_float4(0.f, 0.f, 0.f, 0.f);
            if (row < NPOS) av = *(const float4*)(A + row * 512 + k0 + kq * 4);
            uint2 p;
            p.x = (u32)f2bf(av.x) | ((u32)f2bf(av.y) << 16);
            p.y = (u32)f2bf(av.z) | ((u32)f2bf(av.w) << 16);
            int addr = m * 64 + (((kq >> 1) ^ ((m >> 1) & 3)) << 4) + (kq & 1) * 8;
            *(uint2*)(lds + addr) = p;
        }
        // stage B: 128 n-rows x 32 k bf16 (already bf16 in global)
        #pragma unroll
        for (int u = 0; u < 2; ++u) {
            int idx = u * 256 + t;
            int n = idx >> 2, kb = idx & 3;
            uint4 bv4 = *(const uint4*)(Bw + (size_t)(n0 + n) * 512 + k0 + kb * 8);
            int addr = 8192 + n * 64 + ((kb ^ ((n >> 1) & 3)) << 4);
            *(uint4*)(lds + addr) = bv4;
        }
        __syncthreads();
        short8 af[4], bfr[4];
        #pragma unroll
        for (int mi = 0; mi < 4; ++mi) {
            int m = wm * 64 + mi * 16 + lr;
            af[mi] = *(short8*)(lds + m * 64 + ((lg ^ ((m >> 1) & 3)) << 4));
        }
        #pragma unroll
        for (int ni = 0; ni < 4; ++ni) {
            int n = wn * 64 + ni * 16 + lr;
            bfr[ni] = *(short8*)(lds + 8192 + n * 64 + ((lg ^ ((n >> 1) & 3)) << 4));
        }
        #pragma unroll
        for (int mi = 0; mi < 4; ++mi)
            #pragma unroll
            for (int ni = 0; ni < 4; ++ni)
                acc[mi][ni] = __builtin_amdgcn_mfma_f32_16x16x32_bf16(af[mi], bfr[ni], acc[mi][ni], 0, 0, 0);
        __syncthreads();
    }
    // epilogue: C row = row0 + wm*64 + mi*16 + lg*4 + r ; col = n0 + wn*64 + ni*16 + lr
    if (EPI == 0) {
        #pragma unroll
        for (int ni = 0; ni < 4; ++ni) {
            int col = wn * 64 + ni * 16 + lr;      // 0..127
            float bb = (col < 64) ? b0[col] : b1[col - 64];
            #pragma unroll
            for (int mi = 0; mi < 4; ++mi)
                #pragma unroll
                for (int r = 0; r < 4; ++r) {
                    size_t row = row0 + wm * 64 + mi * 16 + lg * 4 + r;
                    if (row < NPOS) {
                        float v = acc[mi][ni][r] + bb;
                        if (col < 64) o0[row * 64 + col] = v;
                        else          o1[row * 64 + (col - 64)] = v;
                    }
                }
        }
    } else {
        #pragma unroll
        for (int ni = 0; ni < 4; ++ni) {
            int col = n0 + wn * 64 + ni * 16 + lr;
            float bb = b0[col];
            #pragma unroll
            for (int mi = 0; mi < 4; ++mi)
                #pragma unroll
                for (int r = 0; r < 4; ++r) {
                    size_t row = row0 + wm * 64 + mi * 16 + lg * 4 + r;
                    if (row < NPOS) ov[row * 512 + col] = f2bf(acc[mi][ni][r] + bb);
                }
        }
    }
}

// ---------------- eH per (b,w): eH[h][g] = q(h,w)·k(g,w), diag masked ----------------
__global__ __launch_bounds__(256) void att_col(const float* __restrict__ q, const float* __restrict__ k,
                                               float* __restrict__ att) {
    int w = blockIdx.x, b = blockIdx.y;
    __shared__ float Qs[97][68];
    __shared__ float Ks[97][68];
    int t = threadIdx.x;
    for (int u = 0; u < 7; ++u) {
        int h = u * 16 + (t >> 4); int c4 = (t & 15) * 4;
        if (h < 97) {
            size_t base = ((size_t)((b * 97 + h) * 97 + w)) * 64 + c4;
            *(float4*)&Qs[h][c4] = *(const float4*)&q[base];
            *(float4*)&Ks[h][c4] = *(const float4*)&k[base];
        }
    }
    __syncthreads();
    for (int i = t; i < 9409; i += 256) {
        int h = i / 97, g = i - h * 97;
        float s = 0.f;
        #pragma unroll
        for (int c = 0; c < 64; c += 4) {
            float4 a = *(float4*)&Qs[h][c];
            float4 bb = *(float4*)&Ks[g][c];
            s += a.x * bb.x + a.y * bb.y + a.z * bb.z + a.w * bb.w;
        }
        if (g == h) s += NEG_INF_F;
        att[((size_t)((b * 97 + h) * 97 + w)) * ATT + g] = s;
    }
}

// ---------------- eW per (b,h) + fused softmax over concat[eH|eW] ----------------
__global__ __launch_bounds__(256) void att_row_sm(const float* __restrict__ q, const float* __restrict__ k,
                                                  float* __restrict__ att) {
    int h = blockIdx.x, b = blockIdx.y;
    __shared__ float Qs[97][68];
    __shared__ float Ks[97][68];
    __shared__ float Es[16][100];
    int t = threadIdx.x;
    size_t rowbase = (size_t)(b * 97 + h) * 97;
    for (int u = 0; u < 7; ++u) {
        int v = u * 16 + (t >> 4); int c4 = (t & 15) * 4;
        if (v < 97) {
            size_t base = (rowbase + v) * 64 + c4;
            *(float4*)&Qs[v][c4] = *(const float4*)&q[base];
            *(float4*)&Ks[v][c4] = *(const float4*)&k[base];
        }
    }
    __syncthreads();
    int grp = t >> 4, lj = t & 15;
    for (int w0 = 0; w0 < 97; w0 += 16) {
        int wcnt = (97 - w0) < 16 ? (97 - w0) : 16;
        for (int i = t; i < wcnt * 97; i += 256) {
            int wl = i / 97, v = i - wl * 97;
            float s = 0.f;
            #pragma unroll
            for (int c = 0; c < 64; c += 4) {
                float4 a = *(float4*)&Qs[w0 + wl][c];
                float4 bb = *(float4*)&Ks[v][c];
                s += a.x * bb.x + a.y * bb.y + a.z * bb.z + a.w * bb.w;
            }
            Es[wl][v] = s;
        }
        __syncthreads();
        if (grp < wcnt) {
            int w = w0 + grp;
            size_t arow = (rowbase + w) * ATT;
            float vals[13];
            float m = -3.4e38f;
            #pragma unroll
            for (int u = 0; u < 13; ++u) {
                int col = lj + 16 * u;
                float vv = -3.4e38f;
                if (col < ATT) vv = (col < 97) ? att[arow + col] : Es[grp][col - 97];
                vals[u] = vv;
                m = fmaxf(m, vv);
            }
            #pragma unroll
            for (int off = 8; off >= 1; off >>= 1) m = fmaxf(m, __shfl_xor(m, off, 16));
            float ssum = 0.f;
            #pragma unroll
            for (int u = 0; u < 13; ++u) {
                int col = lj + 16 * u;
                if (col < ATT) { vals[u] = __expf(vals[u] - m); ssum += vals[u]; }
            }
            #pragma unroll
            for (int off = 8; off >= 1; off >>= 1) ssum += __shfl_xor(ssum, off, 16);
            float inv = 1.0f / ssum;
            #pragma unroll
            for (int u = 0; u < 13; ++u) {
                int col = lj + 16 * u;
                if (col < ATT) att[arow + col] = vals[u] * inv;
            }
        }
        __syncthreads();
    }
}

// ---------------- column gather (in-place): x[b,h,w,:] = gm*sum_g aH[h,w,g]*v[b,g,w,:] + x[b,h,w,:]
__global__ __launch_bounds__(256) void gath_col(const float* __restrict__ att, const u16* __restrict__ vbf,
                                                const float* __restrict__ gptr, float* __restrict__ x) {
    int b = blockIdx.z, w = blockIdx.y, half = blockIdx.x;
    int h0 = half * 64;
    __shared__ float As[16][68];
    __shared__ float Xs[16][512];
    int t = threadIdx.x, rg = t >> 5, cg = t & 31;
    float acc[8][16] = {{0.f}};
    for (int k0 = 0; k0 < 97; k0 += 16) {
        #pragma unroll
        for (int u = 0; u < 4; ++u) {
            int idx = u * 256 + t, gl = idx & 15, hh = idx >> 4;
            int g = k0 + gl, h = h0 + hh;
            float vv = 0.f;
            if (g < 97 && h < 97) vv = att[((size_t)((b * 97 + h) * 97 + w)) * ATT + g];
            As[gl][hh] = vv;
        }
        #pragma unroll
        for (int u = 0; u < 4; ++u) {
            int f = u * 256 + t; int gl = f >> 6, c8 = (f & 63) * 8;
            int g = k0 + gl;
            if (g < 97) {
                uint4 pv = *(const uint4*)(vbf + ((size_t)((b * 97 + g) * 97 + w)) * 512 + c8);
                u16* pu = (u16*)&pv;
                #pragma unroll
                for (int j = 0; j < 8; ++j) Xs[gl][c8 + j] = bf2f(pu[j]);
            } else {
                #pragma unroll
                for (int j = 0; j < 8; ++j) Xs[gl][c8 + j] = 0.f;
            }
        }
        __syncthreads();
        #pragma unroll
        for (int kk = 0; kk < 16; ++kk) {
            float ra[8];
            *(float4*)&ra[0] = *(float4*)&As[kk][rg * 8];
            *(float4*)&ra[4] = *(float4*)&As[kk][rg * 8 + 4];
            #pragma unroll
            for (int j = 0; j < 16; ++j) {
                float xb = Xs[kk][cg + 32 * j];
                #pragma unroll
                for (int i = 0; i < 8; ++i) acc[i][j] += ra[i] * xb;
            }
        }
        __syncthreads();
    }
    float gm = *gptr;
    #pragma unroll
    for (int i = 0; i < 8; ++i) {
        int h = h0 + rg * 8 + i;
        if (h < 97) {
            size_t base = ((size_t)((b * 97 + h) * 97 + w)) * 512;
            #pragma unroll
            for (int j = 0; j < 16; ++j) {
                size_t o = base + cg + 32 * j;
                x[o] = gm * acc[i][j] + x[o];
            }
        }
    }
}

// ---------------- row gather (in-place add): x[b,h,w,:] += gm*sum_v aW[h,w,v]*v[b,h,v,:]
__global__ __launch_bounds__(256) void gath_row(const float* __restrict__ att, const u16* __restrict__ vbf,
                                                const float* __restrict__ gptr, float* __restrict__ x) {
    int b = blockIdx.z, h = blockIdx.y, half = blockIdx.x;
    int w0 = half * 64;
    __shared__ float As[16][68];
    __shared__ float Xs[16][512];
    int t = threadIdx.x, rg = t >> 5, cg = t & 31;
    float acc[8][16] = {{0.f}};
    size_t rowbase = (size_t)(b * 97 + h) * 97;
    for (int k0 = 0; k0 < 97; k0 += 16) {
        #pragma unroll
        for (int u = 0; u < 4; ++u) {
            int idx = u * 256 + t, gl = idx & 15, wl = idx >> 4;
            int g = k0 + gl, w = w0 + wl;
            float vv = 0.f;
            if (g < 97 && w < 97) vv = att[(rowbase + w) * ATT + 97 + g];
            As[gl][wl] = vv;
        }
        #pragma unroll
        for (int u = 0; u < 4; ++u) {
            int f = u * 256 + t; int gl = f >> 6, c8 = (f & 63) * 8;
            int g = k0 + gl;
            if (g < 97) {
                uint4 pv = *(const uint4*)(vbf + (rowbase + g) * 512 + c8);
                u16* pu = (u16*)&pv;
                #pragma unroll
                for (int j = 0; j < 8; ++j) Xs[gl][c8 + j] = bf2f(pu[j]);
            } else {
                #pragma unroll
                for (int j = 0; j < 8; ++j) Xs[gl][c8 + j] = 0.f;
            }
        }
        __syncthreads();
        #pragma unroll
        for (int kk = 0; kk < 16; ++kk) {
            float ra[8];
            *(float4*)&ra[0] = *(float4*)&As[kk][rg * 8];
            *(float4*)&ra[4] = *(float4*)&As[kk][rg * 8 + 4];
            #pragma unroll
            for (int j = 0; j < 16; ++j) {
                float xb = Xs[kk][cg + 32 * j];
                #pragma unroll
                for (int i = 0; i < 8; ++i) acc[i][j] += ra[i] * xb;
            }
        }
        __syncthreads();
    }
    float gm = *gptr;
    #pragma unroll
    for (int i = 0; i < 8; ++i) {
        int w = w0 + rg * 8 + i;
        if (w < 97) {
            size_t base = (rowbase + w) * 512;
            #pragma unroll
            for (int j = 0; j < 16; ++j) {
                size_t o = base + cg + 32 * j;
                x[o] += gm * acc[i][j];
            }
        }
    }
}

extern "C" void kernel_launch(void* const* d_in, const int* in_sizes, int n_in,
                              void* d_out, int out_size, void* d_ws, size_t ws_size,
                              hipStream_t stream) {
    const float* x_in  = (const float*)d_in[0];
    const float* Wq    = (const float*)d_in[1];
    const float* bq    = (const float*)d_in[2];
    const float* Wk    = (const float*)d_in[3];
    const float* bk    = (const float*)d_in[4];
    const float* Wv    = (const float*)d_in[5];
    const float* bv    = (const float*)d_in[6];
    const float* gamma = (const float*)d_in[7];

    float* ws   = (float*)d_ws;
    float* xA   = ws;                                  // NPOS*512 f32 (canonical x, updated in place)
    float* q    = xA + (size_t)NPOS * CC;              // NPOS*64
    float* kk   = q  + (size_t)NPOS * CI;              // NPOS*64
    float* att  = kk + (size_t)NPOS * CI;              // NPOS*194
    u16*   wqkB = (u16*)(att + (size_t)NPOS * ATT);    // 128*512 bf16 (Wq rows 0-63, Wk rows 64-127)
    u16*   wvB  = wqkB + 128 * 512;                    // 512*512 bf16
    u16*   vbf  = (u16*)d_out;                         // NPOS*512 bf16 (v scratch in d_out)

    cvt_qkw<<<256, 256, 0, stream>>>(Wq, Wk, wqkB);
    cvt_vw<<<1024, 256, 0, stream>>>(Wv, wvB);
    t_in<<<dim3(295, 16, 8), dim3(32, 8), 0, stream>>>(x_in, xA);

    for (int it = 0; it < 2; ++it) {
        gemm_mfma<0><<<dim3(1, 589), 256, 0, stream>>>(xA, wqkB, bq, bk, q, kk, nullptr);
        att_col<<<dim3(97, 8), 256, 0, stream>>>(q, kk, att);
        att_row_sm<<<dim3(97, 8), 256, 0, stream>>>(q, kk, att);
        gemm_mfma<1><<<dim3(4, 589), 256, 0, stream>>>(xA, wvB, bv, nullptr, nullptr, nullptr, vbf);
        gath_col<<<dim3(2, 97, 8), 256, 0, stream>>>(att, vbf, gamma, xA);
        gath_row<<<dim3(2, 97, 8), 256, 0, stream>>>(att, vbf, gamma, xA);
    }
    t_out<<<dim3(295, 16, 8), dim3(32, 8), 0, stream>>>(xA, (float*)d_out);
}